// Round 1
// baseline (21.288 us; speedup 1.0000x reference)
//
#include <hip/hip_runtime.h>
#include <math.h>

// Problem constants
#define NB 2          // batch
#define NC 30         // classes
#define NH 4          // heads
#define HWA 13600     // 100*136
#define HWB 3400      // 50*68
#define PNUM 20
#define CAP2 256
#define LOGIT_TH -2.1972245773362196  // ln(0.1/0.9): sigmoid(x)>0.1 <=> x>this

struct Ptrs {
    const float* cls[8];   // [h*2 + l]
    const float* reg[8];   // [h*2 + l]
    const float* anc[2];   // [l]
};

struct Sh {
    unsigned long long candU[CAP2];
    unsigned tw[4];
    int cw[4];
    int mcnt;
    // per-block results (replaces the old global topv/topi/cnts round-trip)
    float topv[2 * PNUM];
    int   topi[2 * PNUM];
    int   cnt[2];
    // epilogue scratch
    double smv[2 * PNUM];
    int    val[2 * PNUM];
    double k16[2][16];
    int    pk[2];
};

__device__ __forceinline__ unsigned f2key(float x) {
    unsigned u = __float_as_uint(x);
    return (u & 0x80000000u) ? ~u : (u | 0x80000000u);
}

// One level's exact top-20 (+ threshold count) into shared. Safe to call
// repeatedly: leading __syncthreads() fences the previous phase's tail reads
// of candU/mcnt before they are overwritten.
template<int HW, int L>
__device__ __forceinline__ void topk_body(Sh& sh, const float* __restrict__ base) {
    constexpr int N4 = HW / 4;
    constexpr int NV = (N4 + 255) / 256;
    int tid = threadIdx.x, lane = tid & 63, wv = tid >> 6;

    __syncthreads();                 // fence shared-struct reuse across phases
    if (tid == 0) sh.mcnt = 0;

    // Single global pass: values live in registers
    float4 v[NV];
    #pragma unroll
    for (int i = 0; i < NV; ++i) {
        int f = tid + i * 256;
        if (f < N4) v[i] = ((const float4*)base)[f];
    }

    // Per-thread max key + threshold count
    unsigned mk = 0u; int cnt = 0;
    #pragma unroll
    for (int i = 0; i < NV; ++i) {
        int f = tid + i * 256;
        if (f < N4) {
            float xs[4] = {v[i].x, v[i].y, v[i].z, v[i].w};
            #pragma unroll
            for (int j = 0; j < 4; ++j) {
                cnt += ((double)xs[j] > LOGIT_TH);
                unsigned k = f2key(xs[j]);
                mk = (k > mk) ? k : mk;
            }
        }
    }
    // Reduce cnt across wave
    for (int off = 32; off; off >>= 1) cnt += __shfl_down(cnt, off);
    if (lane == 0) sh.cw[wv] = cnt;

    // In-wave bitonic ascending sort of the 64 thread-max keys
    unsigned s = mk;
    #pragma unroll
    for (int k = 2; k <= 64; k <<= 1) {
        #pragma unroll
        for (int j = k >> 1; j > 0; j >>= 1) {
            unsigned o = __shfl_xor(s, j);
            bool up = ((lane & k) == 0);
            bool lower = ((lane & j) == 0);
            s = (up == lower) ? min(s, o) : max(s, o);
        }
    }
    // 20th largest of this wave's maxes = sorted_asc[64 - PNUM]
    unsigned t_w = __shfl(s, 64 - PNUM);
    if (lane == 0) sh.tw[wv] = t_w;
    __syncthreads();

    if (tid == 0) sh.cnt[L] = sh.cw[0] + sh.cw[1] + sh.cw[2] + sh.cw[3];
    unsigned tk = max(max(sh.tw[0], sh.tw[1]), max(sh.tw[2], sh.tw[3]));

    // Collect candidates: key >= tk (guaranteed superset of exact top-20:
    // the wave achieving the max t_w contributes >= 20 elements >= tk)
    #pragma unroll
    for (int i = 0; i < NV; ++i) {
        int f = tid + i * 256;
        if (f < N4) {
            float xs[4] = {v[i].x, v[i].y, v[i].z, v[i].w};
            #pragma unroll
            for (int j = 0; j < 4; ++j) {
                unsigned key = f2key(xs[j]);
                if (key >= tk) {
                    int slot = atomicAdd(&sh.mcnt, 1);
                    if (slot < CAP2) {
                        int eidx = f * 4 + j;
                        sh.candU[slot] = ((unsigned long long)key << 32) |
                                         (unsigned)(~(unsigned)eidx);
                    }
                }
            }
        }
    }
    __syncthreads();

    // Exact rank selection: rank = #{candidates with (key,~idx) strictly greater}
    int M = min(sh.mcnt, CAP2);
    if (tid < M) {
        unsigned long long mu = sh.candU[tid];
        int rank = 0;
        for (int m = 0; m < M; ++m) rank += (sh.candU[m] > mu);
        if (rank < PNUM) {
            unsigned key = (unsigned)(mu >> 32);
            unsigned u = (key & 0x80000000u) ? (key ^ 0x80000000u) : ~key;
            sh.topv[L * PNUM + rank] = __uint_as_float(u);
            sh.topi[L * PNUM + rank] = (int)~(unsigned)(mu & 0xFFFFFFFFu);
        }
    }
}

// Fused kernel: grid = 240 blocks, bid -> (h, n, c). Each block does the
// top-20 for level A and level B, then the full head epilogue from shared.
__global__ __launch_bounds__(256) void k_fused(Ptrs p, float* __restrict__ out) {
    __shared__ Sh sh;
    int bid = blockIdx.x;
    int c = bid % NC; int t = bid / NC;
    int n = t % NB;   int h = t / NB;
    int tid = threadIdx.x;

    // Defensive init (ordered before use by topk_body's leading sync)
    if (tid < 2 * PNUM) { sh.topv[tid] = -1e30f; sh.topi[tid] = 0; }

    topk_body<HWA, 0>(sh, p.cls[h*2 + 0] + (size_t)(n*NC + c) * HWA);
    topk_body<HWB, 1>(sh, p.cls[h*2 + 1] + (size_t)(n*NC + c) * HWB);
    __syncthreads();

    // ---- epilogue (former k_out), all from shared ----
    if (tid < 2 * PNUM) {
        float x = sh.topv[tid];
        int v = ((double)x > LOGIT_TH);
        sh.val[tid] = v;
        sh.smv[tid] = v ? sqrt(1.0 / (1.0 + exp(-(double)x))) : -1e30;
    }
    __syncthreads();

    // gather top-1 box (for size), 32 threads: (l, j)
    if (tid < 32) {
        int l = tid / 16, j = tid % 16;
        int hw = l ? HWB : HWA;
        int pos = sh.topi[l * PNUM];        // argmax index
        const float* reg = p.reg[h*2 + l];
        double r = (double)reg[((size_t)(n*NC*16 + c*16 + j)) * hw + pos];
        const float* anc = p.anc[l];
        double x1 = anc[pos*4+0], y1 = anc[pos*4+1], x2 = anc[pos*4+2], y2 = anc[pos*4+3];
        double kv;
        if (j < 8) kv = r * (x2 - x1) + (x1 + x2) * 0.5;
        else       kv = r * (y2 - y1) + (y1 + y2) * 0.5;
        sh.k16[l][j] = kv;
    }
    __syncthreads();

    if (tid == 0) {
        double best[2], sz[2];
        for (int l = 0; l < 2; ++l) {
            best[l] = sh.smv[l * PNUM];     // NEG if invalid
            double kxmx = -1e300, kxmn = 1e300, kymx = -1e300, kymn = 1e300;
            for (int j = 0; j < 8; ++j) {
                double kx = sh.k16[l][j], ky = sh.k16[l][j + 8];
                kxmx = fmax(kxmx, kx); kxmn = fmin(kxmn, kx);
                kymx = fmax(kymx, ky); kymn = fmin(kymn, ky);
            }
            double s = fmax(kxmx - kxmn, kymx - kymn);
            sz[l] = (best[l] > 0.0) ? s : 0.0;
        }
        int bi = (best[0] >= best[1]) ? 0 : 1;    // argmax, first-max wins
        double box = sz[bi];
        double safe = (box > 0.0) ? box : 1.0;
        double dk0 = log2(safe / 64.0), dk1 = log2(safe / 128.0);
        double e0 = exp(-dk0 * dk0), e1 = exp(-dk1 * dk1);
        double s = e0 + e1;
        int nk0 = (box > 0.0) ? (int)(20.0 * e0 / s + 0.5) : 0;
        int nk1 = (box > 0.0) ? (int)(20.0 * e1 / s + 0.5) : 0;
        sh.pk[0] = min(sh.cnt[0], nk0);
        sh.pk[1] = min(sh.cnt[1], nk1);
    }
    __syncthreads();

    // write outputs: 40 (l,k) items, 17 floats each
    if (tid < 2 * PNUM) {
        int l = tid / PNUM, k = tid % PNUM;
        int hw = l ? HWB : HWA;
        bool v = (k < sh.pk[l]) && sh.val[tid];
        size_t ob = ((((size_t)((n*NH + h)*NC + c)) * 2 + l) * PNUM + k) * 17;
        float* o = out + ob;
        if (!v) {
            #pragma unroll
            for (int e = 0; e < 17; ++e) o[e] = 0.f;
        } else {
            o[0] = (float)sh.smv[tid];
            int pos = sh.topi[tid];
            const float* reg = p.reg[h*2 + l];
            const float* anc = p.anc[l];
            double x1 = anc[pos*4+0], y1 = anc[pos*4+1], x2 = anc[pos*4+2], y2 = anc[pos*4+3];
            double wa = x2 - x1, cxa = (x1 + x2) * 0.5;
            double ha = y2 - y1, cya = (y1 + y2) * 0.5;
            size_t rb = ((size_t)(n*NC*16 + c*16)) * hw + pos;
            #pragma unroll
            for (int j = 0; j < 8; ++j)
                o[1 + j] = (float)((double)reg[rb + (size_t)j * hw] * wa + cxa);
            #pragma unroll
            for (int j = 0; j < 8; ++j)
                o[9 + j] = (float)((double)reg[rb + (size_t)(j + 8) * hw] * ha + cya);
        }
    }
}

extern "C" void kernel_launch(void* const* d_in, const int* in_sizes, int n_in,
                              void* d_out, int out_size, void* d_ws, size_t ws_size,
                              hipStream_t stream) {
    Ptrs p;
    for (int h = 0; h < 4; ++h) {
        p.cls[h*2 + 0] = (const float*)d_in[h*4 + 0];
        p.reg[h*2 + 0] = (const float*)d_in[h*4 + 1];
        p.cls[h*2 + 1] = (const float*)d_in[h*4 + 2];
        p.reg[h*2 + 1] = (const float*)d_in[h*4 + 3];
    }
    p.anc[0] = (const float*)d_in[16];
    p.anc[1] = (const float*)d_in[17];

    k_fused<<<NH * NB * NC, 256, 0, stream>>>(p, (float*)d_out);
}